// Round 20
// baseline (371.055 us; speedup 1.0000x reference)
//
#include <hip/hip_runtime.h>

typedef short bf16x8 __attribute__((ext_vector_type(8)));
typedef short bf16x4 __attribute__((ext_vector_type(4)));
typedef float f32x4 __attribute__((ext_vector_type(4)));
typedef unsigned short u16;

#define GL16(g, l) __builtin_amdgcn_global_load_lds( \
    (const __attribute__((address_space(1))) void*)(g), \
    (__attribute__((address_space(3))) void*)(l), 16, 0, 0)

__device__ __forceinline__ u16 f2bf(float f) {
  union { float f; unsigned u; } v; v.f = f;
  return (u16)((v.u + 0x7fffu + ((v.u >> 16) & 1u)) >> 16);
}

__device__ __forceinline__ float exp2_(float x) {
#if __has_builtin(__builtin_amdgcn_exp2f)
  return __builtin_amdgcn_exp2f(x);
#else
  return __expf(x * 0.69314718056f);
#endif
}

// pack 2 f32 -> 1 u32 of 2 bf16 (RNE), single VALU op
__device__ __forceinline__ unsigned cvtpk(float a, float b) {
  unsigned r;
  asm("v_cvt_pk_bf16_f32 %0, %1, %2" : "=v"(r) : "v"(a), "v"(b));
  return r;
}

// ---------------- LayerNorm: fp32 [rows][1280] -> bf16 ----------------
__global__ __launch_bounds__(256) void ln_kernel(
    const float* __restrict__ x, const float* __restrict__ g,
    const float* __restrict__ b, u16* __restrict__ out) {
  const int row = blockIdx.x, tid = threadIdx.x;
  const float4* xr = (const float4*)(x + (size_t)row * 1280);
  float4 v1 = xr[tid];
  float4 v2 = make_float4(0.f, 0.f, 0.f, 0.f);
  if (tid < 64) v2 = xr[256 + tid];
  float s = v1.x + v1.y + v1.z + v1.w + v2.x + v2.y + v2.z + v2.w;
  float q = v1.x * v1.x + v1.y * v1.y + v1.z * v1.z + v1.w * v1.w +
            v2.x * v2.x + v2.y * v2.y + v2.z * v2.z + v2.w * v2.w;
#pragma unroll
  for (int off = 32; off >= 1; off >>= 1) {
    s += __shfl_xor(s, off);
    q += __shfl_xor(q, off);
  }
  __shared__ float sm[8];
  if ((tid & 63) == 0) { sm[tid >> 6] = s; sm[4 + (tid >> 6)] = q; }
  __syncthreads();
  s = sm[0] + sm[1] + sm[2] + sm[3];
  q = sm[4] + sm[5] + sm[6] + sm[7];
  const float mean = s * (1.0f / 1280.0f);
  const float rstd = rsqrtf(q * (1.0f / 1280.0f) - mean * mean + 1e-5f);
  const float4* gr = (const float4*)g;
  const float4* br = (const float4*)b;
  u16* orow = out + (size_t)row * 1280;
  {
    float4 gg = gr[tid], bb = br[tid];
    ushort4 o;
    o.x = f2bf((v1.x - mean) * rstd * gg.x + bb.x);
    o.y = f2bf((v1.y - mean) * rstd * gg.y + bb.y);
    o.z = f2bf((v1.z - mean) * rstd * gg.z + bb.z);
    o.w = f2bf((v1.w - mean) * rstd * gg.w + bb.w);
    *(ushort4*)&orow[tid * 4] = o;
  }
  if (tid < 64) {
    float4 gg = gr[256 + tid], bb = br[256 + tid];
    ushort4 o;
    o.x = f2bf((v2.x - mean) * rstd * gg.x + bb.x);
    o.y = f2bf((v2.y - mean) * rstd * gg.y + bb.y);
    o.z = f2bf((v2.z - mean) * rstd * gg.z + bb.z);
    o.w = f2bf((v2.w - mean) * rstd * gg.w + bb.w);
    *(ushort4*)&orow[(256 + tid) * 4] = o;
  }
}

// -- transpose + fp32->bf16: dst[c][r] = src[r][c]*scale, 32x64 tile, f4 loads --
__global__ __launch_bounds__(256) void tconv_kernel(
    const float* __restrict__ src, u16* __restrict__ dst,
    int rows, int cols, float scale) {
  __shared__ float t[64][33];
  const int tid = threadIdx.x;
  const size_t c0 = (size_t)blockIdx.x * 64, r0 = (size_t)blockIdx.y * 32;
  const int ty = tid >> 4, col4 = tid & 15;
#pragma unroll
  for (int i = 0; i < 2; ++i) {
    const int row = ty + i * 16;
    float4 v = *(const float4*)&src[(r0 + row) * cols + c0 + col4 * 4];
    t[col4 * 4 + 0][row] = v.x;
    t[col4 * 4 + 1][row] = v.y;
    t[col4 * 4 + 2][row] = v.z;
    t[col4 * 4 + 3][row] = v.w;
  }
  __syncthreads();
  const int c = tid >> 2, rb = (tid & 3) * 8;
  ushort4 o1, o2;
  o1.x = f2bf(t[c][rb + 0] * scale); o1.y = f2bf(t[c][rb + 1] * scale);
  o1.z = f2bf(t[c][rb + 2] * scale); o1.w = f2bf(t[c][rb + 3] * scale);
  o2.x = f2bf(t[c][rb + 4] * scale); o2.y = f2bf(t[c][rb + 5] * scale);
  o2.z = f2bf(t[c][rb + 6] * scale); o2.w = f2bf(t[c][rb + 7] * scale);
  u16* d = &dst[(c0 + c) * rows + r0 + rb];
  *(ushort4*)d = o1;
  *(ushort4*)(d + 4) = o2;
}

// -- fused Wq/Wk/Wv transpose (z selects source): one launch instead of 3 --
__global__ __launch_bounds__(256) void tconv3_kernel(
    const float* __restrict__ s0, const float* __restrict__ s1,
    const float* __restrict__ s2, u16* __restrict__ dst, float scale0) {
  __shared__ float t[64][33];
  const int tid = threadIdx.x, z = blockIdx.z;
  const float* src = (z == 0) ? s0 : ((z == 1) ? s1 : s2);
  const float scale = (z == 0) ? scale0 : 1.0f;
  u16* d0 = dst + (size_t)z * 1280 * 1280;
  const size_t c0 = (size_t)blockIdx.x * 64, r0 = (size_t)blockIdx.y * 32;
  const int ty = tid >> 4, col4 = tid & 15;
#pragma unroll
  for (int i = 0; i < 2; ++i) {
    const int row = ty + i * 16;
    float4 v = *(const float4*)&src[(r0 + row) * 1280 + c0 + col4 * 4];
    t[col4 * 4 + 0][row] = v.x;
    t[col4 * 4 + 1][row] = v.y;
    t[col4 * 4 + 2][row] = v.z;
    t[col4 * 4 + 3][row] = v.w;
  }
  __syncthreads();
  const int c = tid >> 2, rb = (tid & 3) * 8;
  ushort4 o1, o2;
  o1.x = f2bf(t[c][rb + 0] * scale); o1.y = f2bf(t[c][rb + 1] * scale);
  o1.z = f2bf(t[c][rb + 2] * scale); o1.w = f2bf(t[c][rb + 3] * scale);
  o2.x = f2bf(t[c][rb + 4] * scale); o2.y = f2bf(t[c][rb + 5] * scale);
  o2.z = f2bf(t[c][rb + 6] * scale); o2.w = f2bf(t[c][rb + 7] * scale);
  u16* d = &d0[(c0 + c) * 1280 + r0 + rb];
  *(ushort4*)d = o1;
  *(ushort4*)(d + 4) = o2;
}

// ------- per-head V transpose: vt[b][h][d][t] = qkv_v[b*2048+t][h*64+d] -------
__global__ __launch_bounds__(256) void vtrans_kernel(const u16* __restrict__ qkv,
                                                     u16* __restrict__ vt) {
  __shared__ u16 t[64][65];
  const int tx = threadIdx.x & 63, ty = threadIdx.x >> 6;
  const int t0 = blockIdx.x * 64, bh = blockIdx.y, b = bh / 20, h = bh % 20;
  const u16* src = qkv + (size_t)b * 2048 * 3840 + 2560 + h * 64;
  for (int i = ty; i < 64; i += 4) t[i][tx] = src[(size_t)(t0 + i) * 3840 + tx];
  __syncthreads();
  u16* dst = vt + (size_t)bh * 64 * 2048 + t0;
  for (int i = ty; i < 64; i += 4) dst[(size_t)i * 2048 + tx] = t[tx][i];
}

// -------- init: out[r][c] = src[r][c] + bias[c]  (f32, per-float4) --------
__global__ __launch_bounds__(256) void initadd_kernel(
    const float* __restrict__ src, const float* __restrict__ bias,
    float* __restrict__ out) {
  const size_t i = (size_t)blockIdx.x * 256 + threadIdx.x;  // float4 index
  float4 v = ((const float4*)src)[i];
  float4 b = ((const float4*)bias)[i % 320];
  v.x += b.x; v.y += b.y; v.z += b.z; v.w += b.w;
  ((float4*)out)[i] = v;
}

// --------- GEMM 128x128 (r8/r11-proven): SINGLE-barrier, 3-buffer, vmcnt(4) --
// EPI 2: f32 +bias+res (fused)   3: atomicAdd f32
template <int EPI>
__device__ __forceinline__ void gemm_body(
    const u16* __restrict__ A, const u16* __restrict__ BT,
    const float* __restrict__ bias, const float* __restrict__ res,
    void* __restrict__ out, int M, int N, int K, int kSteps) {
  __shared__ __attribute__((aligned(16))) u16 Als[3][128 * 32];
  __shared__ __attribute__((aligned(16))) u16 Bls[3][128 * 32];
  const int tid = threadIdx.x;
  const int w = tid >> 6, lane = tid & 63;
  const int lo = lane & 15, hi = lane >> 4;
  const int wm = w >> 1, wn = w & 1;
  const int gx = gridDim.x, gxy = gx * gridDim.y;
  const int nwg = gxy * gridDim.z;
  int s = blockIdx.x + gx * blockIdx.y + gxy * blockIdx.z;
  s = (s & 7) * (nwg >> 3) + (s >> 3);
  const int bz = s / gxy; s -= bz * gxy;
  const int by = s / gx;  const int bx = s - by * gx;
  const size_t m0 = (size_t)by * 128, n0 = (size_t)bx * 128;
  const int kt0 = bz * kSteps;
  f32x4 acc[4][4] = {};
  const int srow = w * 32 + (lane >> 2);
  const int scol = ((lane & 3) ^ ((lane >> 3) & 3)) * 8;
  const int rsw = (lo >> 1) & 3;          // read-side XOR on col8
#define STAGE(buf, kt)                                                        \
  do {                                                                        \
    const size_t kb = (size_t)(kt) * 32 + scol;                               \
    GL16(&A[(m0 + srow) * K + kb],       &Als[buf][(w * 2 + 0) * 512]);       \
    GL16(&A[(m0 + srow + 16) * K + kb],  &Als[buf][(w * 2 + 1) * 512]);       \
    GL16(&BT[(n0 + srow) * K + kb],      &Bls[buf][(w * 2 + 0) * 512]);       \
    GL16(&BT[(n0 + srow + 16) * K + kb], &Bls[buf][(w * 2 + 1) * 512]);       \
  } while (0)
  STAGE(0, kt0 + 0);
  STAGE(1, kt0 + 1);
  int cur = 0;
  for (int t = 0; t < kSteps; ++t) {
    if (t + 1 < kSteps) asm volatile("s_waitcnt vmcnt(4)" ::: "memory");
    else                asm volatile("s_waitcnt vmcnt(0)" ::: "memory");
    __builtin_amdgcn_s_barrier();
    __builtin_amdgcn_sched_barrier(0);
    const int nxt = (cur == 0) ? 2 : cur - 1;   // (t+2) % 3
    if (t + 2 < kSteps) STAGE(nxt, kt0 + t + 2);
    bf16x8 af[4], bfr[4];
#pragma unroll
    for (int mi = 0; mi < 4; ++mi)
      af[mi] = *(const bf16x8*)&Als[cur][(wm * 64 + mi * 16 + lo) * 32 + ((hi ^ rsw) * 8)];
#pragma unroll
    for (int ni = 0; ni < 4; ++ni)
      bfr[ni] = *(const bf16x8*)&Bls[cur][(wn * 64 + ni * 16 + lo) * 32 + ((hi ^ rsw) * 8)];
#pragma unroll
    for (int mi = 0; mi < 4; ++mi)
#pragma unroll
      for (int ni = 0; ni < 4; ++ni)
        acc[mi][ni] = __builtin_amdgcn_mfma_f32_16x16x32_bf16(
            af[mi], bfr[ni], acc[mi][ni], 0, 0, 0);
    cur = (cur == 2) ? 0 : cur + 1;
  }
#undef STAGE
#pragma unroll
  for (int ni = 0; ni < 4; ++ni) {
    const size_t col = n0 + wn * 64 + ni * 16 + lo;
    const float bv = (EPI == 2) ? bias[col] : 0.0f;
#pragma unroll
    for (int mi = 0; mi < 4; ++mi) {
      const size_t rb = m0 + wm * 64 + mi * 16 + hi * 4;
#pragma unroll
      for (int r = 0; r < 4; ++r) {
        const size_t idx = (rb + r) * N + col;
        float v = acc[mi][ni][r];
        if (EPI == 2) {
          ((float*)out)[idx] = v + bv + res[idx];
        } else {
          atomicAdd(&((float*)out)[idx], v);
        }
      }
    }
  }
}

__global__ __launch_bounds__(256, 3) void gemm_oproj(
    const u16* __restrict__ A, const u16* __restrict__ BT,
    const float* __restrict__ bias, const float* __restrict__ res,
    void* __restrict__ out, int M, int N, int K, int kSteps) {
  gemm_body<2>(A, BT, bias, res, out, M, N, K, kSteps);
}
__global__ __launch_bounds__(256, 3) void gemm_ffn2(
    const u16* __restrict__ A, const u16* __restrict__ BT,
    void* __restrict__ out, int M, int N, int K, int kSteps) {
  gemm_body<3>(A, BT, nullptr, nullptr, out, M, N, K, kSteps);
}

// ===== GEMM 256x256, BK=64, 8 waves, 4-phase deep pipeline ============
// Requires L2/IF$-resident (or just-written-warm) operands (r15/r19 lesson).
// Validated r14/r16 on QKV. EPI 0: bf16   1: bf16+bias+relu
template <int EPI>
__device__ __forceinline__ void gemm8v2_body(
    const u16* __restrict__ A, const u16* __restrict__ BT,
    const float* __restrict__ bias, void* __restrict__ out,
    int M, int N, int K, int nt) {
  __shared__ __attribute__((aligned(16))) u16 Als[2][2][128 * 64]; // [half][slot]
  __shared__ __attribute__((aligned(16))) u16 Bls[2][2][128 * 64];
  const int tid = threadIdx.x;
  const int w = tid >> 6, lane = tid & 63;
  const int lo = lane & 15, hi = lane >> 4;
  const int wm = w >> 2, wn = w & 3;
  const int gx = gridDim.x;
  const int nwg = gx * gridDim.y;
  int s = blockIdx.x + gx * blockIdx.y;
  s = (s & 7) * (nwg >> 3) + (s >> 3);
  const int by = s / gx;  const int bx = s - by * gx;
  const size_t m0 = (size_t)by * 256, n0 = (size_t)bx * 256;
  f32x4 acc[8][4] = {};
  const int srowo = lane >> 3;
  const int gcol = ((lane & 7) ^ (lane >> 3)) * 8;
  const int rsw = lo & 7;
#define STG(dstbuf, srcp, rbase, kt)                                          \
  do {                                                                        \
    const size_t kb = (size_t)(kt) * 64 + gcol;                               \
    GL16(&srcp[(rbase + w * 16 + srowo) * K + kb], &dstbuf[(w * 16) * 64]);   \
    GL16(&srcp[(rbase + w * 16 + 8 + srowo) * K + kb],                        \
         &dstbuf[(w * 16 + 8) * 64]);                                         \
  } while (0)
#define BAR()   __builtin_amdgcn_s_barrier()
#define SB0()   __builtin_amdgcn_sched_barrier(0)
#define LGKM0() asm volatile("s_waitcnt lgkmcnt(0)" ::: "memory")
#define VM6()   asm volatile("s_waitcnt vmcnt(6)" ::: "memory")
#define VM0()   asm volatile("s_waitcnt vmcnt(0)" ::: "memory")
  STG(Als[0][0], A,  m0,       0);
  STG(Bls[0][0], BT, n0,       0);
  STG(Bls[1][0], BT, n0 + 128, 0);
  STG(Als[1][0], A,  m0 + 128, 0);
  for (int t = 0; t < nt; ++t) {
    const int sl = t & 1, sn = sl ^ 1;
    const bool pf = (t + 1 < nt);
    bf16x8 a0[4][2], a1[4][2], b0[2][2], b1[2][2];
    // ---------------- P0: needs A-lo(t), B-lo(t); MFMA Q0 ----------------
    if (pf) { STG(Als[0][sn], A, m0, t + 1); SB0(); VM6(); }
    else    { VM0(); }
    BAR(); SB0();
#pragma unroll
    for (int mi = 0; mi < 4; ++mi)
#pragma unroll
      for (int ks = 0; ks < 2; ++ks)
        a0[mi][ks] = *(const bf16x8*)&Als[0][sl][(wm * 64 + mi * 16 + lo) * 64 +
                                                (((ks * 4 + hi) ^ rsw) * 8)];
#pragma unroll
    for (int ni = 0; ni < 2; ++ni)
#pragma unroll
      for (int ks = 0; ks < 2; ++ks)
        b0[ni][ks] = *(const bf16x8*)&Bls[0][sl][(wn * 32 + ni * 16 + lo) * 64 +
                                                (((ks * 4 + hi) ^ rsw) * 8)];
    LGKM0(); SB0();
    __builtin_amdgcn_s_setprio(1);
#pragma unroll
    for (int mi = 0; mi < 4; ++mi)
#pragma unroll
      for (int ni = 0; ni < 2; ++ni)
#pragma unroll
        for (int ks = 0; ks < 2; ++ks)
          acc[mi][ni] = __builtin_amdgcn_mfma_f32_16x16x32_bf16(
              a0[mi][ks], b0[ni][ks], acc[mi][ni], 0, 0, 0);
    __builtin_amdgcn_s_setprio(0);
    // ---------------- P1: needs B-hi(t); MFMA Q1 ----------------
    if (pf) { STG(Bls[0][sn], BT, n0, t + 1); SB0(); VM6(); }
    else    { VM0(); }
    BAR(); SB0();
#pragma unroll
    for (int ni = 0; ni < 2; ++ni)
#pragma unroll
      for (int ks = 0; ks < 2; ++ks)
        b1[ni][ks] = *(const bf16x8*)&Bls[1][sl][(wn * 32 + ni * 16 + lo) * 64 +
                                                (((ks * 4 + hi) ^ rsw) * 8)];
    LGKM0(); SB0();
    __builtin_amdgcn_s_setprio(1);
#pragma unroll
    for (int mi = 0; mi < 4; ++mi)
#pragma unroll
      for (int ni = 0; ni < 2; ++ni)
#pragma unroll
        for (int ks = 0; ks < 2; ++ks)
          acc[mi][ni + 2] = __builtin_amdgcn_mfma_f32_16x16x32_bf16(
              a0[mi][ks], b1[ni][ks], acc[mi][ni + 2], 0, 0, 0);
    __builtin_amdgcn_s_setprio(0);
    // ---------------- P2: needs A-hi(t); MFMA Q2 ----------------
    if (pf) { STG(Bls[1][sn], BT, n0 + 128, t + 1); SB0(); VM6(); }
    else    { VM0(); }
    BAR(); SB0();
#pragma unroll
    for (int mi = 0; mi < 4; ++mi)
#pragma unroll
      for (int ks = 0; ks < 2; ++ks)
        a1[mi][ks] = *(const bf16x8*)&Als[1][sl][(wm * 64 + mi * 16 + lo) * 64 +
                                                (((ks * 4 + hi) ^ rsw) * 8)];
    LGKM0(); SB0();
    __builtin_amdgcn_s_setprio(1);
#pragma unroll
    for (int mi = 0; mi < 4; ++mi)
#pragma unroll
      for (int ni = 0; ni < 2; ++ni)
#pragma unroll
        for (int ks = 0; ks < 2; ++ks)
          acc[mi + 4][ni] = __builtin_amdgcn_mfma_f32_16x16x32_bf16(
              a1[mi][ks], b0[ni][ks], acc[mi + 4][ni], 0, 0, 0);
    __builtin_amdgcn_s_setprio(0);
    // ---------------- P3: reg-only MFMA Q3 (no wait/barrier) ----------------
    if (pf) STG(Als[1][sn], A, m0 + 128, t + 1);
    SB0();
    __builtin_amdgcn_s_setprio(1);
#pragma unroll
    for (int mi = 0; mi < 4; ++mi)
#pragma unroll
      for (int ni = 0; ni < 2; ++ni)
#pragma unroll
        for (int ks = 0; ks < 2; ++ks)
          acc[mi + 4][ni + 2] = __builtin_amdgcn_mfma_f32_16x16x32_bf16(
              a1[mi][ks], b1[ni][ks], acc[mi + 4][ni + 2], 0, 0, 0);
    __builtin_amdgcn_s_setprio(0);
  }
#undef STG
#undef BAR
#undef SB0
#undef LGKM0
#undef VM6
#undef VM0
#pragma unroll
  for (int ni = 0; ni < 4; ++ni) {
    const int ncol = (ni < 2) ? (wn * 32 + ni * 16) : (128 + wn * 32 + (ni - 2) * 16);
    const size_t col = n0 + ncol + lo;
    const float bv = (EPI == 1) ? bias[col] : 0.0f;
#pragma unroll
    for (int mi = 0; mi < 8; ++mi) {
      const int mrow = (mi < 4) ? (wm * 64 + mi * 16) : (128 + wm * 64 + (mi - 4) * 16);
      const size_t rb = m0 + mrow + hi * 4;
#pragma unroll
      for (int r = 0; r < 4; ++r) {
        const size_t idx = (rb + r) * N + col;
        float v = acc[mi][ni][r];
        if (EPI == 1) {
          v += bv;
          v = fmaxf(v, 0.0f);
          ((u16*)out)[idx] = f2bf(v);
        } else {
          ((u16*)out)[idx] = f2bf(v);
        }
      }
    }
  }
}

__global__ __launch_bounds__(512, 2) void gemm_qkv8(
    const u16* __restrict__ A, const u16* __restrict__ BT,
    void* __restrict__ out, int M, int N, int K, int nt) {
  gemm8v2_body<0>(A, BT, nullptr, out, M, N, K, nt);
}
__global__ __launch_bounds__(512, 2) void gemm_ffn18(
    const u16* __restrict__ A, const u16* __restrict__ BT,
    const float* __restrict__ bias, void* __restrict__ out,
    int M, int N, int K, int nt) {
  gemm8v2_body<1>(A, BT, bias, out, M, N, K, nt);
}

// ------------- flash attention: 1 block = (b,h) x 128 q rows, 8 waves --------
// r13/r16 proven config.
__global__ __launch_bounds__(512) void attn_kernel(
    const u16* __restrict__ qkv, const u16* __restrict__ vt,
    u16* __restrict__ aout) {
  __shared__ __attribute__((aligned(16))) u16 Klds[64 * 64];
  __shared__ __attribute__((aligned(16))) u16 Vlds[64 * 64];
  __shared__ __attribute__((aligned(16))) u16 Plds[8][16][72];  // +8 pad
  const int tid = threadIdx.x;
  const int w = tid >> 6, lane = tid & 63;   // w = 0..7
  const int lo = lane & 15, hi = lane >> 4;
  const int bh = blockIdx.x, qt = blockIdx.y;   // bh-major => same XCD per bh
  const int b = bh / 20, h = bh % 20;
  const size_t qrow = (size_t)b * 2048 + qt * 128 + w * 16 + lo;
  bf16x8 qf[2];
  qf[0] = *(const bf16x8*)&qkv[qrow * 3840 + h * 64 + hi * 8];
  qf[1] = *(const bf16x8*)&qkv[qrow * 3840 + h * 64 + 32 + hi * 8];
  float m_i = -1e30f, l_i = 0.0f;
  f32x4 accO[4] = {};
  const int srow = lane >> 3;                   // 0..7 within chunk
  const int scol = ((lane & 7) ^ srow) * 8;     // inverse-swizzled global col
  const u16* kbase = qkv + (size_t)b * 2048 * 3840 + 1280 + h * 64;
  const u16* vbase = vt + (size_t)bh * 64 * 2048;
  for (int kt = 0; kt < 32; ++kt) {
    {  // wave w stages chunk w (8 rows) of K and of V
      const int row = w * 8 + srow;
      GL16(kbase + (size_t)(kt * 64 + row) * 3840 + scol, &Klds[w * 512]);
      GL16(vbase + (size_t)row * 2048 + kt * 64 + scol, &Vlds[w * 512]);
    }
    __syncthreads();
    // S^T = mfma(K, Q): lane -> q=lo, kv = st*16 + hi*4 + r   (log2 domain)
    f32x4 s4[4] = {};
    __builtin_amdgcn_s_setprio(1);
#pragma unroll
    for (int st = 0; st < 4; ++st) {
      const int row = st * 16 + lo;
      const int sw = (row & 7) << 3;
#pragma unroll
      for (int ks = 0; ks < 2; ++ks) {
        bf16x8 a = *(const bf16x8*)&Klds[row * 64 + ((ks * 32 + hi * 8) ^ sw)];
        s4[st] = __builtin_amdgcn_mfma_f32_16x16x32_bf16(a, qf[ks], s4[st], 0, 0, 0);
      }
    }
    __builtin_amdgcn_s_setprio(0);
    // online softmax in log2 domain; tile max across the 4 lanes per q-row
    float tm = fmaxf(fmaxf(fmaxf(s4[0][0], s4[0][1]), fmaxf(s4[0][2], s4[0][3])),
                     fmaxf(fmaxf(s4[1][0], s4[1][1]), fmaxf(s4[1][2], s4[1][3])));
    tm = fmaxf(tm, fmaxf(fmaxf(fmaxf(s4[2][0], s4[2][1]), fmaxf(s4[2][2], s4[2][3])),
                         fmaxf(fmaxf(s4[3][0], s4[3][1]), fmaxf(s4[3][2], s4[3][3]))));
    tm = fmaxf(tm, __shfl_xor(tm, 16));
    tm = fmaxf(tm, __shfl_xor(tm, 32));
    // T13 defer-max: only rescale when the tile max exceeds m_i + 8
    if (!__all(tm <= m_i + 8.0f)) {
      const float mnew = fmaxf(m_i, tm);
      const float corr = exp2_(m_i - mnew);
      m_i = mnew;
      l_i *= corr;
      float cr[4];
#pragma unroll
      for (int r = 0; r < 4; ++r) cr[r] = __shfl(corr, hi * 4 + r);
#pragma unroll
      for (int d = 0; d < 4; ++d)
#pragma unroll
        for (int r = 0; r < 4; ++r) accO[d][r] *= cr[r];
    }
#pragma unroll
    for (int st = 0; st < 4; ++st)
#pragma unroll
      for (int r = 0; r < 4; ++r) {
        const float p = exp2_(s4[st][r] - m_i);
        s4[st][r] = p;
        l_i += p;      // per-lane partial; reduced after the loop
      }
    // P -> LDS (per-wave private region), 2x cvt_pk per st
#pragma unroll
    for (int st = 0; st < 4; ++st) {
      uint2 pk;
      pk.x = cvtpk(s4[st][0], s4[st][1]);
      pk.y = cvtpk(s4[st][2], s4[st][3]);
      *(uint2*)&Plds[w][lo][st * 16 + hi * 4] = pk;
    }
    asm volatile("s_waitcnt lgkmcnt(0)" ::: "memory");
    __builtin_amdgcn_sched_barrier(0);
    // O += P @ V  (A=P from Plds, B=V from swizzled V^T tile)
    __builtin_amdgcn_s_setprio(1);
#pragma unroll
    for (int ks = 0; ks < 2; ++ks) {
      bf16x8 pa = *(const bf16x8*)&Plds[w][lo][ks * 32 + hi * 8];
#pragma unroll
      for (int d = 0; d < 4; ++d) {
        const int row = d * 16 + lo;
        bf16x8 vb = *(const bf16x8*)
            &Vlds[row * 64 + ((ks * 32 + hi * 8) ^ ((row & 7) << 3))];
        accO[d] = __builtin_amdgcn_mfma_f32_16x16x32_bf16(pa, vb, accO[d], 0, 0, 0);
      }
    }
    __builtin_amdgcn_s_setprio(0);
    __syncthreads();   // all reads done before next iter's stage overwrites
  }
  // reduce per-lane l partials across the 4 hi-groups of each q-row
  l_i += __shfl_xor(l_i, 16);
  l_i += __shfl_xor(l_i, 32);
  float linv[4];
#pragma unroll
  for (int r = 0; r < 4; ++r) linv[r] = 1.0f / __shfl(l_i, hi * 4 + r);
  const size_t orow0 = (size_t)b * 2048 + qt * 128 + w * 16 + hi * 4;
#pragma unroll
  for (int d = 0; d < 4; ++d)
#pragma unroll
    for (int r = 0; r < 4; ++r)
      aout[(orow0 + r) * 1280 + h * 64 + d * 16 + lo] =
          f2bf(accO[d][r] * linv[r]);
}

extern "C" void kernel_launch(void* const* d_in, const int* in_sizes, int n_in,
                              void* d_out, int out_size, void* d_ws, size_t ws_size,
                              hipStream_t stream) {
  const float* x   = (const float*)d_in[0];
  const float* Wq  = (const float*)d_in[2];
  const float* Wk  = (const float*)d_in[3];
  const float* Wv  = (const float*)d_in[4];
  const float* Wo  = (const float*)d_in[5];
  const float* bo  = (const float*)d_in[6];
  const float* W1  = (const float*)d_in[7];
  const float* b1  = (const float*)d_in[8];
  const float* W2  = (const float*)d_in[9];
  const float* b2  = (const float*)d_in[10];
  const float* g1  = (const float*)d_in[11];
  const float* be1 = (const float*)d_in[12];
  const float* g2  = (const float*)d_in[13];
  const float* be2 = (const float*)d_in[14];

  // workspace layout (~123 MB): hbuf aliases qkvb+vtb (dead by then)
  u16* xn   = (u16*)d_ws;                       // 4096x1280
  u16* Wqkv = xn + (size_t)4096 * 1280;         // 3840x1280 (WqT|WkT|WvT)
  u16* WoT  = Wqkv + (size_t)3840 * 1280;       // 1280x1280
  u16* W1T  = WoT + (size_t)1280 * 1280;        // 5120x1280
  u16* W2T  = W1T + (size_t)5120 * 1280;        // 1280x5120
  u16* aOut = W2T + (size_t)1280 * 5120;        // 4096x1280
  float* x1 = (float*)(aOut + (size_t)4096 * 1280);  // 4096x1280 f32
  u16* qkvb = (u16*)(x1 + (size_t)4096 * 1280); // 4096x3840
  u16* vtb  = qkvb + (size_t)4096 * 3840;       // 40x64x2048
  u16* hbuf = qkvb;                             // alias: 4096x5120

  // 0.125 (1/sqrt(64)) * log2(e): scores come out of QK^T in log2 domain
  const float qscale = 0.125f * 1.4426950408889634f;
  // Weight transposes placed immediately before their consumer GEMM (warm B).
  ln_kernel<<<4096, 256, 0, stream>>>(x, g1, be1, xn);
  tconv3_kernel<<<dim3(20, 40, 3), 256, 0, stream>>>(Wq, Wk, Wv, Wqkv, qscale);
  // QKV on the deep-pipelined 256^2 kernel (operands warm: xn + Wqkv)
  gemm_qkv8<<<dim3(15, 16), 512, 0, stream>>>(xn, Wqkv, qkvb, 4096, 3840, 1280, 20);
  vtrans_kernel<<<dim3(32, 40), 256, 0, stream>>>(qkvb, vtb);
  attn_kernel<<<dim3(40, 16), 512, 0, stream>>>(qkvb, vtb, aOut);
  tconv_kernel<<<dim3(20, 40), 256, 0, stream>>>(Wo, WoT, 1280, 1280, 1.0f);
  // O-proj: fused epilogue (x1 = aOut@WoT + bo + x)
  gemm_oproj<<<dim3(10, 32), 256, 0, stream>>>(aOut, WoT, bo, x, x1, 4096, 1280, 1280, 40);
  ln_kernel<<<4096, 256, 0, stream>>>(x1, g2, be2, xn);
  tconv_kernel<<<dim3(80, 40), 256, 0, stream>>>(W1, W1T, 1280, 5120, 1.0f);
  // FFN1 on the deep pipeline: operands xn (just written) + W1T (just written)
  // are L2-warm -> same regime as QKV (r19 re-test of r15's cold-operand fail)
  gemm_ffn18<<<dim3(20, 16), 512, 0, stream>>>(xn, W1T, b1, hbuf, 4096, 5120, 1280, 20);
  // d_out = x1 + b2, then FFN2 split-K(2) atomicAdds into it (proven 128^2)
  initadd_kernel<<<5120, 256, 0, stream>>>(x1, b2, (float*)d_out);
  tconv_kernel<<<dim3(20, 160), 256, 0, stream>>>(W2, W2T, 5120, 1280, 1.0f);
  gemm_ffn2<<<dim3(10, 32, 2), 256, 0, stream>>>(hbuf, W2T, d_out, 4096, 1280, 5120, 80);
  (void)in_sizes; (void)n_in; (void)out_size; (void)ws_size;
}

// Round 21
// 365.709 us; speedup vs baseline: 1.0146x; 1.0146x over previous
//
#include <hip/hip_runtime.h>

typedef short bf16x8 __attribute__((ext_vector_type(8)));
typedef short bf16x4 __attribute__((ext_vector_type(4)));
typedef float f32x4 __attribute__((ext_vector_type(4)));
typedef unsigned short u16;

#define GL16(g, l) __builtin_amdgcn_global_load_lds( \
    (const __attribute__((address_space(1))) void*)(g), \
    (__attribute__((address_space(3))) void*)(l), 16, 0, 0)

__device__ __forceinline__ u16 f2bf(float f) {
  union { float f; unsigned u; } v; v.f = f;
  return (u16)((v.u + 0x7fffu + ((v.u >> 16) & 1u)) >> 16);
}

__device__ __forceinline__ float exp2_(float x) {
#if __has_builtin(__builtin_amdgcn_exp2f)
  return __builtin_amdgcn_exp2f(x);
#else
  return __expf(x * 0.69314718056f);
#endif
}

// pack 2 f32 -> 1 u32 of 2 bf16 (RNE), single VALU op
__device__ __forceinline__ unsigned cvtpk(float a, float b) {
  unsigned r;
  asm("v_cvt_pk_bf16_f32 %0, %1, %2" : "=v"(r) : "v"(a), "v"(b));
  return r;
}

// ---------------- LayerNorm: fp32 [rows][1280] -> bf16 ----------------
__global__ __launch_bounds__(256) void ln_kernel(
    const float* __restrict__ x, const float* __restrict__ g,
    const float* __restrict__ b, u16* __restrict__ out) {
  const int row = blockIdx.x, tid = threadIdx.x;
  const float4* xr = (const float4*)(x + (size_t)row * 1280);
  float4 v1 = xr[tid];
  float4 v2 = make_float4(0.f, 0.f, 0.f, 0.f);
  if (tid < 64) v2 = xr[256 + tid];
  float s = v1.x + v1.y + v1.z + v1.w + v2.x + v2.y + v2.z + v2.w;
  float q = v1.x * v1.x + v1.y * v1.y + v1.z * v1.z + v1.w * v1.w +
            v2.x * v2.x + v2.y * v2.y + v2.z * v2.z + v2.w * v2.w;
#pragma unroll
  for (int off = 32; off >= 1; off >>= 1) {
    s += __shfl_xor(s, off);
    q += __shfl_xor(q, off);
  }
  __shared__ float sm[8];
  if ((tid & 63) == 0) { sm[tid >> 6] = s; sm[4 + (tid >> 6)] = q; }
  __syncthreads();
  s = sm[0] + sm[1] + sm[2] + sm[3];
  q = sm[4] + sm[5] + sm[6] + sm[7];
  const float mean = s * (1.0f / 1280.0f);
  const float rstd = rsqrtf(q * (1.0f / 1280.0f) - mean * mean + 1e-5f);
  const float4* gr = (const float4*)g;
  const float4* br = (const float4*)b;
  u16* orow = out + (size_t)row * 1280;
  {
    float4 gg = gr[tid], bb = br[tid];
    ushort4 o;
    o.x = f2bf((v1.x - mean) * rstd * gg.x + bb.x);
    o.y = f2bf((v1.y - mean) * rstd * gg.y + bb.y);
    o.z = f2bf((v1.z - mean) * rstd * gg.z + bb.z);
    o.w = f2bf((v1.w - mean) * rstd * gg.w + bb.w);
    *(ushort4*)&orow[tid * 4] = o;
  }
  if (tid < 64) {
    float4 gg = gr[256 + tid], bb = br[256 + tid];
    ushort4 o;
    o.x = f2bf((v2.x - mean) * rstd * gg.x + bb.x);
    o.y = f2bf((v2.y - mean) * rstd * gg.y + bb.y);
    o.z = f2bf((v2.z - mean) * rstd * gg.z + bb.z);
    o.w = f2bf((v2.w - mean) * rstd * gg.w + bb.w);
    *(ushort4*)&orow[(256 + tid) * 4] = o;
  }
}

// -- transpose + fp32->bf16: dst[c][r] = src[r][c]*scale, 32x64 tile, f4 loads --
__global__ __launch_bounds__(256) void tconv_kernel(
    const float* __restrict__ src, u16* __restrict__ dst,
    int rows, int cols, float scale) {
  __shared__ float t[64][33];
  const int tid = threadIdx.x;
  const size_t c0 = (size_t)blockIdx.x * 64, r0 = (size_t)blockIdx.y * 32;
  const int ty = tid >> 4, col4 = tid & 15;
#pragma unroll
  for (int i = 0; i < 2; ++i) {
    const int row = ty + i * 16;
    float4 v = *(const float4*)&src[(r0 + row) * cols + c0 + col4 * 4];
    t[col4 * 4 + 0][row] = v.x;
    t[col4 * 4 + 1][row] = v.y;
    t[col4 * 4 + 2][row] = v.z;
    t[col4 * 4 + 3][row] = v.w;
  }
  __syncthreads();
  const int c = tid >> 2, rb = (tid & 3) * 8;
  ushort4 o1, o2;
  o1.x = f2bf(t[c][rb + 0] * scale); o1.y = f2bf(t[c][rb + 1] * scale);
  o1.z = f2bf(t[c][rb + 2] * scale); o1.w = f2bf(t[c][rb + 3] * scale);
  o2.x = f2bf(t[c][rb + 4] * scale); o2.y = f2bf(t[c][rb + 5] * scale);
  o2.z = f2bf(t[c][rb + 6] * scale); o2.w = f2bf(t[c][rb + 7] * scale);
  u16* d = &dst[(c0 + c) * rows + r0 + rb];
  *(ushort4*)d = o1;
  *(ushort4*)(d + 4) = o2;
}

// -- fused Wq/Wk/Wv transpose (z selects source): one launch instead of 3 --
__global__ __launch_bounds__(256) void tconv3_kernel(
    const float* __restrict__ s0, const float* __restrict__ s1,
    const float* __restrict__ s2, u16* __restrict__ dst, float scale0) {
  __shared__ float t[64][33];
  const int tid = threadIdx.x, z = blockIdx.z;
  const float* src = (z == 0) ? s0 : ((z == 1) ? s1 : s2);
  const float scale = (z == 0) ? scale0 : 1.0f;
  u16* d0 = dst + (size_t)z * 1280 * 1280;
  const size_t c0 = (size_t)blockIdx.x * 64, r0 = (size_t)blockIdx.y * 32;
  const int ty = tid >> 4, col4 = tid & 15;
#pragma unroll
  for (int i = 0; i < 2; ++i) {
    const int row = ty + i * 16;
    float4 v = *(const float4*)&src[(r0 + row) * 1280 + c0 + col4 * 4];
    t[col4 * 4 + 0][row] = v.x;
    t[col4 * 4 + 1][row] = v.y;
    t[col4 * 4 + 2][row] = v.z;
    t[col4 * 4 + 3][row] = v.w;
  }
  __syncthreads();
  const int c = tid >> 2, rb = (tid & 3) * 8;
  ushort4 o1, o2;
  o1.x = f2bf(t[c][rb + 0] * scale); o1.y = f2bf(t[c][rb + 1] * scale);
  o1.z = f2bf(t[c][rb + 2] * scale); o1.w = f2bf(t[c][rb + 3] * scale);
  o2.x = f2bf(t[c][rb + 4] * scale); o2.y = f2bf(t[c][rb + 5] * scale);
  o2.z = f2bf(t[c][rb + 6] * scale); o2.w = f2bf(t[c][rb + 7] * scale);
  u16* d = &d0[(c0 + c) * 1280 + r0 + rb];
  *(ushort4*)d = o1;
  *(ushort4*)(d + 4) = o2;
}

// ------- per-head V transpose: vt[b][h][d][t] = qkv_v[b*2048+t][h*64+d] -------
__global__ __launch_bounds__(256) void vtrans_kernel(const u16* __restrict__ qkv,
                                                     u16* __restrict__ vt) {
  __shared__ u16 t[64][65];
  const int tx = threadIdx.x & 63, ty = threadIdx.x >> 6;
  const int t0 = blockIdx.x * 64, bh = blockIdx.y, b = bh / 20, h = bh % 20;
  const u16* src = qkv + (size_t)b * 2048 * 3840 + 2560 + h * 64;
  for (int i = ty; i < 64; i += 4) t[i][tx] = src[(size_t)(t0 + i) * 3840 + tx];
  __syncthreads();
  u16* dst = vt + (size_t)bh * 64 * 2048 + t0;
  for (int i = ty; i < 64; i += 4) dst[(size_t)i * 2048 + tx] = t[tx][i];
}

// -------- init: out[r][c] = src[r][c] + bias[c]  (f32, per-float4) --------
__global__ __launch_bounds__(256) void initadd_kernel(
    const float* __restrict__ src, const float* __restrict__ bias,
    float* __restrict__ out) {
  const size_t i = (size_t)blockIdx.x * 256 + threadIdx.x;  // float4 index
  float4 v = ((const float4*)src)[i];
  float4 b = ((const float4*)bias)[i % 320];
  v.x += b.x; v.y += b.y; v.z += b.z; v.w += b.w;
  ((float4*)out)[i] = v;
}

// --------- GEMM 128x128 (r8/r11-proven): SINGLE-barrier, 3-buffer, vmcnt(4) --
// EPI 1: bf16+bias+relu   2: f32 +bias+res (fused)   3: atomicAdd f32
template <int EPI>
__device__ __forceinline__ void gemm_body(
    const u16* __restrict__ A, const u16* __restrict__ BT,
    const float* __restrict__ bias, const float* __restrict__ res,
    void* __restrict__ out, int M, int N, int K, int kSteps) {
  __shared__ __attribute__((aligned(16))) u16 Als[3][128 * 32];
  __shared__ __attribute__((aligned(16))) u16 Bls[3][128 * 32];
  const int tid = threadIdx.x;
  const int w = tid >> 6, lane = tid & 63;
  const int lo = lane & 15, hi = lane >> 4;
  const int wm = w >> 1, wn = w & 1;
  const int gx = gridDim.x, gxy = gx * gridDim.y;
  const int nwg = gxy * gridDim.z;
  int s = blockIdx.x + gx * blockIdx.y + gxy * blockIdx.z;
  s = (s & 7) * (nwg >> 3) + (s >> 3);
  const int bz = s / gxy; s -= bz * gxy;
  const int by = s / gx;  const int bx = s - by * gx;
  const size_t m0 = (size_t)by * 128, n0 = (size_t)bx * 128;
  const int kt0 = bz * kSteps;
  f32x4 acc[4][4] = {};
  const int srow = w * 32 + (lane >> 2);
  const int scol = ((lane & 3) ^ ((lane >> 3) & 3)) * 8;
  const int rsw = (lo >> 1) & 3;          // read-side XOR on col8
#define STAGE(buf, kt)                                                        \
  do {                                                                        \
    const size_t kb = (size_t)(kt) * 32 + scol;                               \
    GL16(&A[(m0 + srow) * K + kb],       &Als[buf][(w * 2 + 0) * 512]);       \
    GL16(&A[(m0 + srow + 16) * K + kb],  &Als[buf][(w * 2 + 1) * 512]);       \
    GL16(&BT[(n0 + srow) * K + kb],      &Bls[buf][(w * 2 + 0) * 512]);       \
    GL16(&BT[(n0 + srow + 16) * K + kb], &Bls[buf][(w * 2 + 1) * 512]);       \
  } while (0)
  STAGE(0, kt0 + 0);
  STAGE(1, kt0 + 1);
  int cur = 0;
  for (int t = 0; t < kSteps; ++t) {
    if (t + 1 < kSteps) asm volatile("s_waitcnt vmcnt(4)" ::: "memory");
    else                asm volatile("s_waitcnt vmcnt(0)" ::: "memory");
    __builtin_amdgcn_s_barrier();
    __builtin_amdgcn_sched_barrier(0);
    const int nxt = (cur == 0) ? 2 : cur - 1;   // (t+2) % 3
    if (t + 2 < kSteps) STAGE(nxt, kt0 + t + 2);
    bf16x8 af[4], bfr[4];
#pragma unroll
    for (int mi = 0; mi < 4; ++mi)
      af[mi] = *(const bf16x8*)&Als[cur][(wm * 64 + mi * 16 + lo) * 32 + ((hi ^ rsw) * 8)];
#pragma unroll
    for (int ni = 0; ni < 4; ++ni)
      bfr[ni] = *(const bf16x8*)&Bls[cur][(wn * 64 + ni * 16 + lo) * 32 + ((hi ^ rsw) * 8)];
#pragma unroll
    for (int mi = 0; mi < 4; ++mi)
#pragma unroll
      for (int ni = 0; ni < 4; ++ni)
        acc[mi][ni] = __builtin_amdgcn_mfma_f32_16x16x32_bf16(
            af[mi], bfr[ni], acc[mi][ni], 0, 0, 0);
    cur = (cur == 2) ? 0 : cur + 1;
  }
#undef STAGE
#pragma unroll
  for (int ni = 0; ni < 4; ++ni) {
    const size_t col = n0 + wn * 64 + ni * 16 + lo;
    const float bv = (EPI == 1 || EPI == 2) ? bias[col] : 0.0f;
#pragma unroll
    for (int mi = 0; mi < 4; ++mi) {
      const size_t rb = m0 + wm * 64 + mi * 16 + hi * 4;
#pragma unroll
      for (int r = 0; r < 4; ++r) {
        const size_t idx = (rb + r) * N + col;
        float v = acc[mi][ni][r];
        if (EPI == 1) {
          v += bv;
          v = fmaxf(v, 0.0f);
          ((u16*)out)[idx] = f2bf(v);
        } else if (EPI == 2) {
          ((float*)out)[idx] = v + bv + res[idx];
        } else {
          atomicAdd(&((float*)out)[idx], v);
        }
      }
    }
  }
}

__global__ __launch_bounds__(256, 3) void gemm_oproj(
    const u16* __restrict__ A, const u16* __restrict__ BT,
    const float* __restrict__ bias, const float* __restrict__ res,
    void* __restrict__ out, int M, int N, int K, int kSteps) {
  gemm_body<2>(A, BT, bias, res, out, M, N, K, kSteps);
}
__global__ __launch_bounds__(256, 3) void gemm_ffn1(
    const u16* __restrict__ A, const u16* __restrict__ BT,
    const float* __restrict__ bias, void* __restrict__ out,
    int M, int N, int K, int kSteps) {
  gemm_body<1>(A, BT, bias, nullptr, out, M, N, K, kSteps);
}
__global__ __launch_bounds__(256, 3) void gemm_ffn2(
    const u16* __restrict__ A, const u16* __restrict__ BT,
    void* __restrict__ out, int M, int N, int K, int kSteps) {
  gemm_body<3>(A, BT, nullptr, nullptr, out, M, N, K, kSteps);
}

// ===== GEMM 256x256, BK=64, 8 waves, 4-phase deep pipeline (QKV only) =====
// Validity domain (r14/r15/r20): single warm operand pair ~20 MB, first
// consumer after producer, ~240-block grid. Validated on QKV only.
__global__ __launch_bounds__(512, 2) void gemm_qkv8(
    const u16* __restrict__ A, const u16* __restrict__ BT,
    void* __restrict__ out, int M, int N, int K, int nt) {
  __shared__ __attribute__((aligned(16))) u16 Als[2][2][128 * 64]; // [half][slot]
  __shared__ __attribute__((aligned(16))) u16 Bls[2][2][128 * 64];
  const int tid = threadIdx.x;
  const int w = tid >> 6, lane = tid & 63;
  const int lo = lane & 15, hi = lane >> 4;
  const int wm = w >> 2, wn = w & 3;
  const int gx = gridDim.x;
  const int nwg = gx * gridDim.y;
  int s = blockIdx.x + gx * blockIdx.y;
  s = (s & 7) * (nwg >> 3) + (s >> 3);
  const int by = s / gx;  const int bx = s - by * gx;
  const size_t m0 = (size_t)by * 256, n0 = (size_t)bx * 256;
  f32x4 acc[8][4] = {};
  const int srowo = lane >> 3;
  const int gcol = ((lane & 7) ^ (lane >> 3)) * 8;
  const int rsw = lo & 7;
#define STG(dstbuf, srcp, rbase, kt)                                          \
  do {                                                                        \
    const size_t kb = (size_t)(kt) * 64 + gcol;                               \
    GL16(&srcp[(rbase + w * 16 + srowo) * K + kb], &dstbuf[(w * 16) * 64]);   \
    GL16(&srcp[(rbase + w * 16 + 8 + srowo) * K + kb],                        \
         &dstbuf[(w * 16 + 8) * 64]);                                         \
  } while (0)
#define BAR()   __builtin_amdgcn_s_barrier()
#define SB0()   __builtin_amdgcn_sched_barrier(0)
#define LGKM0() asm volatile("s_waitcnt lgkmcnt(0)" ::: "memory")
#define VM6()   asm volatile("s_waitcnt vmcnt(6)" ::: "memory")
#define VM0()   asm volatile("s_waitcnt vmcnt(0)" ::: "memory")
  STG(Als[0][0], A,  m0,       0);
  STG(Bls[0][0], BT, n0,       0);
  STG(Bls[1][0], BT, n0 + 128, 0);
  STG(Als[1][0], A,  m0 + 128, 0);
  for (int t = 0; t < nt; ++t) {
    const int sl = t & 1, sn = sl ^ 1;
    const bool pf = (t + 1 < nt);
    bf16x8 a0[4][2], a1[4][2], b0[2][2], b1[2][2];
    // ---------------- P0: needs A-lo(t), B-lo(t); MFMA Q0 ----------------
    if (pf) { STG(Als[0][sn], A, m0, t + 1); SB0(); VM6(); }
    else    { VM0(); }
    BAR(); SB0();
#pragma unroll
    for (int mi = 0; mi < 4; ++mi)
#pragma unroll
      for (int ks = 0; ks < 2; ++ks)
        a0[mi][ks] = *(const bf16x8*)&Als[0][sl][(wm * 64 + mi * 16 + lo) * 64 +
                                                (((ks * 4 + hi) ^ rsw) * 8)];
#pragma unroll
    for (int ni = 0; ni < 2; ++ni)
#pragma unroll
      for (int ks = 0; ks < 2; ++ks)
        b0[ni][ks] = *(const bf16x8*)&Bls[0][sl][(wn * 32 + ni * 16 + lo) * 64 +
                                                (((ks * 4 + hi) ^ rsw) * 8)];
    LGKM0(); SB0();
    __builtin_amdgcn_s_setprio(1);
#pragma unroll
    for (int mi = 0; mi < 4; ++mi)
#pragma unroll
      for (int ni = 0; ni < 2; ++ni)
#pragma unroll
        for (int ks = 0; ks < 2; ++ks)
          acc[mi][ni] = __builtin_amdgcn_mfma_f32_16x16x32_bf16(
              a0[mi][ks], b0[ni][ks], acc[mi][ni], 0, 0, 0);
    __builtin_amdgcn_s_setprio(0);
    // ---------------- P1: needs B-hi(t); MFMA Q1 ----------------
    if (pf) { STG(Bls[0][sn], BT, n0, t + 1); SB0(); VM6(); }
    else    { VM0(); }
    BAR(); SB0();
#pragma unroll
    for (int ni = 0; ni < 2; ++ni)
#pragma unroll
      for (int ks = 0; ks < 2; ++ks)
        b1[ni][ks] = *(const bf16x8*)&Bls[1][sl][(wn * 32 + ni * 16 + lo) * 64 +
                                                (((ks * 4 + hi) ^ rsw) * 8)];
    LGKM0(); SB0();
    __builtin_amdgcn_s_setprio(1);
#pragma unroll
    for (int mi = 0; mi < 4; ++mi)
#pragma unroll
      for (int ni = 0; ni < 2; ++ni)
#pragma unroll
        for (int ks = 0; ks < 2; ++ks)
          acc[mi][ni + 2] = __builtin_amdgcn_mfma_f32_16x16x32_bf16(
              a0[mi][ks], b1[ni][ks], acc[mi][ni + 2], 0, 0, 0);
    __builtin_amdgcn_s_setprio(0);
    // ---------------- P2: needs A-hi(t); MFMA Q2 ----------------
    if (pf) { STG(Bls[1][sn], BT, n0 + 128, t + 1); SB0(); VM6(); }
    else    { VM0(); }
    BAR(); SB0();
#pragma unroll
    for (int mi = 0; mi < 4; ++mi)
#pragma unroll
      for (int ks = 0; ks < 2; ++ks)
        a1[mi][ks] = *(const bf16x8*)&Als[1][sl][(wm * 64 + mi * 16 + lo) * 64 +
                                                (((ks * 4 + hi) ^ rsw) * 8)];
    LGKM0(); SB0();
    __builtin_amdgcn_s_setprio(1);
#pragma unroll
    for (int mi = 0; mi < 4; ++mi)
#pragma unroll
      for (int ni = 0; ni < 2; ++ni)
#pragma unroll
        for (int ks = 0; ks < 2; ++ks)
          acc[mi + 4][ni] = __builtin_amdgcn_mfma_f32_16x16x32_bf16(
              a1[mi][ks], b0[ni][ks], acc[mi + 4][ni], 0, 0, 0);
    __builtin_amdgcn_s_setprio(0);
    // ---------------- P3: reg-only MFMA Q3 (no wait/barrier) ----------------
    if (pf) STG(Als[1][sn], A, m0 + 128, t + 1);
    SB0();
    __builtin_amdgcn_s_setprio(1);
#pragma unroll
    for (int mi = 0; mi < 4; ++mi)
#pragma unroll
      for (int ni = 0; ni < 2; ++ni)
#pragma unroll
        for (int ks = 0; ks < 2; ++ks)
          acc[mi + 4][ni + 2] = __builtin_amdgcn_mfma_f32_16x16x32_bf16(
              a1[mi][ks], b1[ni][ks], acc[mi + 4][ni + 2], 0, 0, 0);
    __builtin_amdgcn_s_setprio(0);
  }
#undef STG
#undef BAR
#undef SB0
#undef LGKM0
#undef VM6
#undef VM0
#pragma unroll
  for (int ni = 0; ni < 4; ++ni) {
    const int ncol = (ni < 2) ? (wn * 32 + ni * 16) : (128 + wn * 32 + (ni - 2) * 16);
    const size_t col = n0 + ncol + lo;
#pragma unroll
    for (int mi = 0; mi < 8; ++mi) {
      const int mrow = (mi < 4) ? (wm * 64 + mi * 16) : (128 + wm * 64 + (mi - 4) * 16);
      const size_t rb = m0 + mrow + hi * 4;
#pragma unroll
      for (int r = 0; r < 4; ++r) {
        const size_t idx = (rb + r) * N + col;
        ((u16*)out)[idx] = f2bf(acc[mi][ni][r]);
      }
    }
  }
}

// ------------- flash attention: 1 block = (b,h) x 128 q rows, 8 waves --------
// r13/r16 proven config.
__global__ __launch_bounds__(512) void attn_kernel(
    const u16* __restrict__ qkv, const u16* __restrict__ vt,
    u16* __restrict__ aout) {
  __shared__ __attribute__((aligned(16))) u16 Klds[64 * 64];
  __shared__ __attribute__((aligned(16))) u16 Vlds[64 * 64];
  __shared__ __attribute__((aligned(16))) u16 Plds[8][16][72];  // +8 pad
  const int tid = threadIdx.x;
  const int w = tid >> 6, lane = tid & 63;   // w = 0..7
  const int lo = lane & 15, hi = lane >> 4;
  const int bh = blockIdx.x, qt = blockIdx.y;   // bh-major => same XCD per bh
  const int b = bh / 20, h = bh % 20;
  const size_t qrow = (size_t)b * 2048 + qt * 128 + w * 16 + lo;
  bf16x8 qf[2];
  qf[0] = *(const bf16x8*)&qkv[qrow * 3840 + h * 64 + hi * 8];
  qf[1] = *(const bf16x8*)&qkv[qrow * 3840 + h * 64 + 32 + hi * 8];
  float m_i = -1e30f, l_i = 0.0f;
  f32x4 accO[4] = {};
  const int srow = lane >> 3;                   // 0..7 within chunk
  const int scol = ((lane & 7) ^ srow) * 8;     // inverse-swizzled global col
  const u16* kbase = qkv + (size_t)b * 2048 * 3840 + 1280 + h * 64;
  const u16* vbase = vt + (size_t)bh * 64 * 2048;
  for (int kt = 0; kt < 32; ++kt) {
    {  // wave w stages chunk w (8 rows) of K and of V
      const int row = w * 8 + srow;
      GL16(kbase + (size_t)(kt * 64 + row) * 3840 + scol, &Klds[w * 512]);
      GL16(vbase + (size_t)row * 2048 + kt * 64 + scol, &Vlds[w * 512]);
    }
    __syncthreads();
    // S^T = mfma(K, Q): lane -> q=lo, kv = st*16 + hi*4 + r   (log2 domain)
    f32x4 s4[4] = {};
    __builtin_amdgcn_s_setprio(1);
#pragma unroll
    for (int st = 0; st < 4; ++st) {
      const int row = st * 16 + lo;
      const int sw = (row & 7) << 3;
#pragma unroll
      for (int ks = 0; ks < 2; ++ks) {
        bf16x8 a = *(const bf16x8*)&Klds[row * 64 + ((ks * 32 + hi * 8) ^ sw)];
        s4[st] = __builtin_amdgcn_mfma_f32_16x16x32_bf16(a, qf[ks], s4[st], 0, 0, 0);
      }
    }
    __builtin_amdgcn_s_setprio(0);
    // online softmax in log2 domain; tile max across the 4 lanes per q-row
    float tm = fmaxf(fmaxf(fmaxf(s4[0][0], s4[0][1]), fmaxf(s4[0][2], s4[0][3])),
                     fmaxf(fmaxf(s4[1][0], s4[1][1]), fmaxf(s4[1][2], s4[1][3])));
    tm = fmaxf(tm, fmaxf(fmaxf(fmaxf(s4[2][0], s4[2][1]), fmaxf(s4[2][2], s4[2][3])),
                         fmaxf(fmaxf(s4[3][0], s4[3][1]), fmaxf(s4[3][2], s4[3][3]))));
    tm = fmaxf(tm, __shfl_xor(tm, 16));
    tm = fmaxf(tm, __shfl_xor(tm, 32));
    // T13 defer-max: only rescale when the tile max exceeds m_i + 8
    if (!__all(tm <= m_i + 8.0f)) {
      const float mnew = fmaxf(m_i, tm);
      const float corr = exp2_(m_i - mnew);
      m_i = mnew;
      l_i *= corr;
      float cr[4];
#pragma unroll
      for (int r = 0; r < 4; ++r) cr[r] = __shfl(corr, hi * 4 + r);
#pragma unroll
      for (int d = 0; d < 4; ++d)
#pragma unroll
        for (int r = 0; r < 4; ++r) accO[d][r] *= cr[r];
    }
#pragma unroll
    for (int st = 0; st < 4; ++st)
#pragma unroll
      for (int r = 0; r < 4; ++r) {
        const float p = exp2_(s4[st][r] - m_i);
        s4[st][r] = p;
        l_i += p;      // per-lane partial; reduced after the loop
      }
    // P -> LDS (per-wave private region), 2x cvt_pk per st
#pragma unroll
    for (int st = 0; st < 4; ++st) {
      uint2 pk;
      pk.x = cvtpk(s4[st][0], s4[st][1]);
      pk.y = cvtpk(s4[st][2], s4[st][3]);
      *(uint2*)&Plds[w][lo][st * 16 + hi * 4] = pk;
    }
    asm volatile("s_waitcnt lgkmcnt(0)" ::: "memory");
    __builtin_amdgcn_sched_barrier(0);
    // O += P @ V  (A=P from Plds, B=V from swizzled V^T tile)
    __builtin_amdgcn_s_setprio(1);
#pragma unroll
    for (int ks = 0; ks < 2; ++ks) {
      bf16x8 pa = *(const bf16x8*)&Plds[w][lo][ks * 32 + hi * 8];
#pragma unroll
      for (int d = 0; d < 4; ++d) {
        const int row = d * 16 + lo;
        bf16x8 vb = *(const bf16x8*)
            &Vlds[row * 64 + ((ks * 32 + hi * 8) ^ ((row & 7) << 3))];
        accO[d] = __builtin_amdgcn_mfma_f32_16x16x32_bf16(pa, vb, accO[d], 0, 0, 0);
      }
    }
    __builtin_amdgcn_s_setprio(0);
    __syncthreads();   // all reads done before next iter's stage overwrites
  }
  // reduce per-lane l partials across the 4 hi-groups of each q-row
  l_i += __shfl_xor(l_i, 16);
  l_i += __shfl_xor(l_i, 32);
  float linv[4];
#pragma unroll
  for (int r = 0; r < 4; ++r) linv[r] = 1.0f / __shfl(l_i, hi * 4 + r);
  const size_t orow0 = (size_t)b * 2048 + qt * 128 + w * 16 + hi * 4;
#pragma unroll
  for (int d = 0; d < 4; ++d)
#pragma unroll
    for (int r = 0; r < 4; ++r)
      aout[(orow0 + r) * 1280 + h * 64 + d * 16 + lo] =
          f2bf(accO[d][r] * linv[r]);
}

extern "C" void kernel_launch(void* const* d_in, const int* in_sizes, int n_in,
                              void* d_out, int out_size, void* d_ws, size_t ws_size,
                              hipStream_t stream) {
  const float* x   = (const float*)d_in[0];
  const float* Wq  = (const float*)d_in[2];
  const float* Wk  = (const float*)d_in[3];
  const float* Wv  = (const float*)d_in[4];
  const float* Wo  = (const float*)d_in[5];
  const float* bo  = (const float*)d_in[6];
  const float* W1  = (const float*)d_in[7];
  const float* b1  = (const float*)d_in[8];
  const float* W2  = (const float*)d_in[9];
  const float* b2  = (const float*)d_in[10];
  const float* g1  = (const float*)d_in[11];
  const float* be1 = (const float*)d_in[12];
  const float* g2  = (const float*)d_in[13];
  const float* be2 = (const float*)d_in[14];

  // workspace layout (~123 MB): hbuf aliases qkvb+vtb (dead by then)
  u16* xn   = (u16*)d_ws;                       // 4096x1280
  u16* Wqkv = xn + (size_t)4096 * 1280;         // 3840x1280 (WqT|WkT|WvT)
  u16* WoT  = Wqkv + (size_t)3840 * 1280;       // 1280x1280
  u16* W1T  = WoT + (size_t)1280 * 1280;        // 5120x1280
  u16* W2T  = W1T + (size_t)5120 * 1280;        // 1280x5120
  u16* aOut = W2T + (size_t)1280 * 5120;        // 4096x1280
  float* x1 = (float*)(aOut + (size_t)4096 * 1280);  // 4096x1280 f32
  u16* qkvb = (u16*)(x1 + (size_t)4096 * 1280); // 4096x3840
  u16* vtb  = qkvb + (size_t)4096 * 3840;       // 40x64x2048
  u16* hbuf = qkvb;                             // alias: 4096x5120

  // 0.125 (1/sqrt(64)) * log2(e): scores come out of QK^T in log2 domain
  const float qscale = 0.125f * 1.4426950408889634f;
  // Weight transposes placed immediately before their consumer GEMM (warm B).
  ln_kernel<<<4096, 256, 0, stream>>>(x, g1, be1, xn);
  tconv3_kernel<<<dim3(20, 40, 3), 256, 0, stream>>>(Wq, Wk, Wv, Wqkv, qscale);
  // QKV on the deep-pipelined 256^2 kernel (operands warm: xn + Wqkv)
  gemm_qkv8<<<dim3(15, 16), 512, 0, stream>>>(xn, Wqkv, qkvb, 4096, 3840, 1280, 20);
  vtrans_kernel<<<dim3(32, 40), 256, 0, stream>>>(qkvb, vtb);
  attn_kernel<<<dim3(40, 16), 512, 0, stream>>>(qkvb, vtb, aOut);
  tconv_kernel<<<dim3(20, 40), 256, 0, stream>>>(Wo, WoT, 1280, 1280, 1.0f);
  // O-proj: fused epilogue (x1 = aOut@WoT + bo + x)
  gemm_oproj<<<dim3(10, 32), 256, 0, stream>>>(aOut, WoT, bo, x, x1, 4096, 1280, 1280, 40);
  ln_kernel<<<4096, 256, 0, stream>>>(x1, g2, be2, xn);
  tconv_kernel<<<dim3(80, 40), 256, 0, stream>>>(W1, W1T, 1280, 5120, 1.0f);
  gemm_ffn1<<<dim3(40, 32), 256, 0, stream>>>(xn, W1T, b1, hbuf, 4096, 5120, 1280, 40);
  // d_out = x1 + b2, then FFN2 split-K(2) atomicAdds into it (proven 128^2)
  initadd_kernel<<<5120, 256, 0, stream>>>(x1, b2, (float*)d_out);
  tconv_kernel<<<dim3(20, 160), 256, 0, stream>>>(W2, W2T, 5120, 1280, 1.0f);
  gemm_ffn2<<<dim3(10, 32, 2), 256, 0, stream>>>(hbuf, W2T, d_out, 4096, 1280, 5120, 80);
  (void)in_sizes; (void)n_in; (void)out_size; (void)ws_size;
}